// Round 4
// baseline (338.862 us; speedup 1.0000x reference)
//
#include <hip/hip_runtime.h>

// ---------------- problem constants ----------------
#define N_ANCH 221184      // H*W*A = 128*192*9
#define HW     24576       // H*W
#define Wd     192
#define AA     9
#define TOPN   6000
#define POSTN  300
#define CAND_CAP 8192
#define NWORDS 94          // ceil(6016/64) words of suppression bits
#define NCHUNK 47          // 6016 / 128

typedef unsigned long long u64;
typedef __attribute__((ext_vector_type(2))) unsigned long long u64x2;

// anchor widths/heights (== ws2/hs2 of the reference, exact small ints)
__device__ const float c_aw[9] = {184.f,368.f,736.f,128.f,256.f,512.f, 88.f,176.f,352.f};
__device__ const float c_ah[9] = { 96.f,192.f,384.f,128.f,256.f,512.f,176.f,352.f,704.f};

// shared box decode — used by decode_kernel AND rank_scatter so the FP
// sequence (and thus every bit of the box) is identical in both places.
__device__ __forceinline__ float4 decode_box(int a, int cell,
                                             const float* __restrict__ deltas,
                                             float info0, float info1, float info2,
                                             bool* valid) {
    int h = cell / Wd;
    int w = cell - h * Wd;
    const float* db = deltas + (size_t)(4 * a) * HW + cell;
    float dx = db[0];
    float dy = db[HW];
    float dw = db[2 * HW];
    float dh = db[3 * HW];
    dw = fminf(fmaxf(dw, -10.f), 10.f);
    dh = fminf(fmaxf(dh, -10.f), 10.f);

    float ww = c_aw[a], hh = c_ah[a];
    float cx = 16.f * (float)w + 8.f;   // exact
    float cy = 16.f * (float)h + 8.f;   // exact

    float pcx = __fadd_rn(__fmul_rn(dx, ww), cx);
    float pcy = __fadd_rn(__fmul_rn(dy, hh), cy);
    float pw  = __fmul_rn(expf(dw), ww);
    float ph  = __fmul_rn(expf(dh), hh);
    float hpw = __fmul_rn(0.5f, pw);
    float hph = __fmul_rn(0.5f, ph);
    float x1 = __fsub_rn(pcx, hpw);
    float x2 = __fadd_rn(pcx, hpw);
    float y1 = __fsub_rn(pcy, hph);
    float y2 = __fadd_rn(pcy, hph);

    float xmax = __fsub_rn(info1, 1.f);
    float ymax = __fsub_rn(info0, 1.f);
    x1 = fminf(fmaxf(x1, 0.f), xmax);
    x2 = fminf(fmaxf(x2, 0.f), xmax);
    y1 = fminf(fmaxf(y1, 0.f), ymax);
    y2 = fminf(fmaxf(y2, 0.f), ymax);

    float msz = __fmul_rn(16.f, info2);
    *valid = (__fadd_rn(__fsub_rn(x2, x1), 1.f) >= msz) &&
             (__fadd_rn(__fsub_rn(y2, y1), 1.f) >= msz);
    return make_float4(x1, y1, x2, y2);
}

// ---------------- init: zero hist256+state+cand (contiguous) + vmask ------
#define ZA_F4 4164    // (1024 + 64 + 65536) / 16
#define ZB_F4 48      // 768 / 16
__global__ __launch_bounds__(256) void init_kernel(float4* zA, float4* zB) {
    int t = blockIdx.x * 256 + threadIdx.x;
    float4 z = make_float4(0.f, 0.f, 0.f, 0.f);
    if (t < ZA_F4) zA[t] = z;
    else if (t < ZA_F4 + ZB_F4) zB[t - ZA_F4] = z;
}

__global__ __launch_bounds__(256) void decode_kernel(const float* __restrict__ scores,
                                                     const float* __restrict__ deltas,
                                                     const float* __restrict__ iminfo,
                                                     unsigned int* __restrict__ keys,
                                                     unsigned int* __restrict__ hist256) {
    __shared__ unsigned int lh[256];
    lh[threadIdx.x] = 0u;
    __syncthreads();
    int t = blockIdx.x * 256 + threadIdx.x;
    int a = t / HW;
    int cell = t - a * HW;
    float score = scores[(AA + a) * HW + cell];
    bool valid;
    (void)decode_box(a, cell, deltas, iminfo[0], iminfo[1], iminfo[2], &valid);
    unsigned int sb = __float_as_uint(score);
    unsigned int key = valid ? ((sb & 0x80000000u) ? ~sb : (sb | 0x80000000u))
                             : 0x007FFFFFu;
    keys[t] = key;
    atomicAdd(&lh[key >> 24], 1u);
    __syncthreads();
    if (lh[threadIdx.x]) atomicAdd(&hist256[threadIdx.x], lh[threadIdx.x]);
}

__global__ __launch_bounds__(1024) void midselect_kernel(const unsigned int* __restrict__ keys,
                                                         const unsigned int* __restrict__ hist256,
                                                         unsigned int* __restrict__ state) {
    __shared__ unsigned int sfx[256];
    __shared__ unsigned int h2w[16][256];
    __shared__ unsigned int sP, sRank;
    int t = threadIdx.x;
    int wv = t >> 6;
    for (int i = t; i < 16 * 256; i += 1024) ((unsigned int*)h2w)[i] = 0u;
    if (t < 256) sfx[t] = hist256[t];
    __syncthreads();
    for (int d = 1; d < 256; d <<= 1) {
        unsigned int v = 0u;
        if (t < 256 && t + d < 256) v = sfx[t + d];
        __syncthreads();
        if (t < 256) sfx[t] += v;
        __syncthreads();
    }
    if (t < 256) {
        unsigned int ge = sfx[t];
        unsigned int gt = (t < 255) ? sfx[t + 1] : 0u;
        if (ge >= TOPN && gt < TOPN) { sP = (unsigned int)t; sRank = TOPN - gt; }
    }
    __syncthreads();
    unsigned int P = sP, rank = sRank;
    const uint4* k4 = (const uint4*)keys;
    for (int i = t; i < N_ANCH / 4; i += 1024) {
        uint4 v = k4[i];
        if ((v.x >> 24) == P) atomicAdd(&h2w[wv][(v.x >> 16) & 0xFFu], 1u);
        if ((v.y >> 24) == P) atomicAdd(&h2w[wv][(v.y >> 16) & 0xFFu], 1u);
        if ((v.z >> 24) == P) atomicAdd(&h2w[wv][(v.z >> 16) & 0xFFu], 1u);
        if ((v.w >> 24) == P) atomicAdd(&h2w[wv][(v.w >> 16) & 0xFFu], 1u);
    }
    __syncthreads();
    if (t < 256) {
        unsigned int s = 0;
        #pragma unroll
        for (int wvi = 0; wvi < 16; ++wvi) s += h2w[wvi][t];
        sfx[t] = s;
    }
    __syncthreads();
    for (int d = 1; d < 256; d <<= 1) {
        unsigned int v = 0u;
        if (t < 256 && t + d < 256) v = sfx[t + d];
        __syncthreads();
        if (t < 256) sfx[t] += v;
        __syncthreads();
    }
    if (t < 256) {
        unsigned int ge = sfx[t];
        unsigned int gt = (t < 255) ? sfx[t + 1] : 0u;
        if (ge >= rank && gt < rank) {
            state[0] = (P << 24) | ((unsigned int)t << 16);
            state[2] = 0u;
        }
    }
}

__global__ __launch_bounds__(256) void compact_kernel(const unsigned int* __restrict__ keys,
                                                      unsigned int* __restrict__ state,
                                                      u64* __restrict__ cand) {
    int t = blockIdx.x * 256 + threadIdx.x;
    unsigned int k = keys[t];
    unsigned int T = state[0];
    if (k >= T) {
        unsigned int pos = atomicAdd(&state[2], 1u);
        if (pos < CAND_CAP) {
            int a = t / HW;
            int cell = t - a * HW;
            unsigned int aidx = (unsigned int)(cell * 9 + a);
            cand[pos] = ((u64)k << 32) | (u64)(~aidx);
        }
    }
}

__global__ __launch_bounds__(256) void rank_scatter_kernel(const u64* __restrict__ cand,
                                                           const float* __restrict__ deltas,
                                                           const float* __restrict__ iminfo,
                                                           float4* __restrict__ tb,
                                                           u64* __restrict__ vmask) {
    __shared__ u64 s[CAND_CAP];
    for (int j = threadIdx.x; j < CAND_CAP; j += 256) s[j] = cand[j];
    int part = threadIdx.x & 7;
    int i = blockIdx.x * 32 + (threadIdx.x >> 3);
    u64 k = cand[i];
    __syncthreads();
    const ulonglong2* sv = (const ulonglong2*)s;
    unsigned int cnt = 0;
    #pragma unroll 8
    for (int jj = part; jj < CAND_CAP / 2; jj += 8) {
        ulonglong2 v = sv[jj];
        cnt += (v.x > k) ? 1u : 0u;
        cnt += (v.y > k) ? 1u : 0u;
    }
    cnt += __shfl_xor(cnt, 1);
    cnt += __shfl_xor(cnt, 2);
    cnt += __shfl_xor(cnt, 4);
    if (part == 0 && k != 0ull && cnt < TOPN) {
        unsigned int aidx = ~((unsigned int)k);
        int a = (int)(aidx % 9u);
        int cell = (int)(aidx / 9u);
        bool valid;
        float4 box = decode_box(a, cell, deltas, iminfo[0], iminfo[1], iminfo[2], &valid);
        tb[cnt] = box;
        if ((unsigned int)(k >> 32) != 0x007FFFFFu)
            atomicOr(&vmask[cnt >> 6], 1ull << (cnt & 63));
    }
}

// suppression bit-matrix, upper-triangle word-blocks only.
__global__ __launch_bounds__(64) void nms_matrix_kernel(const float4* __restrict__ tb,
                                                        u64* __restrict__ mat) {
    if (blockIdx.x < blockIdx.y) return;
    __shared__ float4 cb[64];
    int t = threadIdx.x;
    int c0 = blockIdx.x * 64;
    int col = c0 + t;
    cb[t] = (col < TOPN) ? tb[col] : make_float4(0.f, 0.f, 0.f, 0.f);
    __syncthreads();
    int row = blockIdx.y * 64 + t;
    if (row >= TOPN) return;
    float4 rb = tb[row];
    float rA = (rb.z - rb.x) * (rb.w - rb.y);
    u64 mask = 0ull;
    for (int c = 0; c < 64; ++c) {
        if (c0 + c >= TOPN) break;
        float4 b = cb[c];
        float lx = fmaxf(rb.x, b.x), ly = fmaxf(rb.y, b.y);
        float rx = fminf(rb.z, b.z), ry = fminf(rb.w, b.w);
        float iw = fmaxf(rx - lx, 0.f), ih = fmaxf(ry - ly, 0.f);
        float inter = iw * ih;
        float bA = (b.z - b.x) * (b.w - b.y);
        float iou = inter / ((rA + bA) - inter);
        if (iou > 0.7f) mask |= (1ull << c);
    }
    mat[(size_t)row * NWORDS + blockIdx.x] = mask;
}

// 64-bit readlane with wave-uniform index.
__device__ __forceinline__ u64 rdl64(u64 v, int l) {
    unsigned int lo = (unsigned int)__builtin_amdgcn_readlane((int)(unsigned int)v, l);
    unsigned int hi = (unsigned int)__builtin_amdgcn_readlane((int)(unsigned int)(v >> 32), l);
    return ((u64)hi << 32) | (u64)lo;
}

// ---- inline-asm loads: cannot be sunk/elided/rematerialized by the
// compiler (rounds 1-3 all died to load sinking). Waits are MANUAL. ----
__device__ __forceinline__ u64 aload_b64(const u64* p) {
    u64 d;
    asm volatile("global_load_dwordx2 %0, %1, off"
                 : "=v"(d) : "v"((u64)(uintptr_t)p));
    return d;
}
__device__ __forceinline__ u64x2 aload_b128(const u64* p) {
    u64x2 d;
    asm volatile("global_load_dwordx4 %0, %1, off"
                 : "=v"(d) : "v"((u64)(uintptr_t)p));
    return d;
}
// steady-state counted wait: keep the newest 22 VMEM ops in flight
// (= 6 diag loads of D(c+2-ish) + 16 row loads of rows(c-1)/rows(c)),
// wait everything older (= D(c) and rows(c-2), both >=1 chunk old).
__device__ __forceinline__ void vmwait22() {
    asm volatile("s_waitcnt vmcnt(22)" ::: "memory");
}

// Extended diagonal block for chunk c, per lane:
//  a  = words 2c,2c+1   of rows c*128+lane / +64+lane  (this chunk's cols)
//  ax = words 2c+2,2c+3 (next chunk's cols -> nx)
//  aq = words 2c+4,2c+5 (next-next chunk's cols -> nq), clamped at the end
struct Dx { u64x2 a, ax, aq, b, bx, bq; };

__device__ __forceinline__ void issue_d(int c, int lane, const u64* mat, Dx& D) {
    int cc = (c < NCHUNK) ? c : (NCHUNK - 1);
    const u64* rowA = mat + (size_t)(cc * 128 + lane) * NWORDS;
    const u64* rowB = rowA + (size_t)64 * NWORDS;
    int o0 = 2 * cc;
    int o1 = (o0 + 2 <= NWORDS - 2) ? o0 + 2 : NWORDS - 2;
    int o2 = (o0 + 4 <= NWORDS - 2) ? o0 + 4 : NWORDS - 2;
    D.a  = aload_b128(rowA + o0);
    D.ax = aload_b128(rowA + o1);
    D.aq = aload_b128(rowA + o2);
    D.b  = aload_b128(rowB + o0);
    D.bx = aload_b128(rowB + o1);
    D.bq = aload_b128(rowB + o2);
}

// Always issue exactly 16 row loads (8 slots x 2 words) so vmcnt counts are
// static. Dead slots load the chunk base row and are masked via plive.
__device__ __forceinline__ void issue_rows(int base, int lane, const u64* mat,
                                           u64 k0, u64 k1,
                                           u64 (&pv0)[8], u64 (&pv1)[8],
                                           unsigned& plive,
                                           u64& r0, u64& r1, int l1w) {
    u64 m0 = k0, m1 = k1;
    unsigned lv = 0u;
    #pragma unroll
    for (int j = 0; j < 8; ++j) {
        int b = -1;
        if (m0)      { b = __ffsll(m0) - 1;      m0 &= m0 - 1; }
        else if (m1) { b = 64 + __ffsll(m1) - 1; m1 &= m1 - 1; }
        int bS = (b >= 0) ? b : 0;
        const u64* row = mat + (size_t)(base + bS) * NWORDS;
        pv0[j] = aload_b64(row + lane);
        pv1[j] = aload_b64(row + l1w);
        lv |= (b >= 0) ? (1u << j) : 0u;
    }
    plive = lv;
    // extras (>8 kept in one chunk — rare): synchronous fold. Their nx/nq
    // bits were accumulated in greedy, so only r needs them (early is fine:
    // r is a monotone OR-accumulator of true suppression data).
    while (m0 | m1) {
        int b;
        if (m0) { b = __ffsll(m0) - 1; m0 &= m0 - 1; }
        else    { b = 64 + __ffsll(m1) - 1; m1 &= m1 - 1; }
        const u64* row = mat + (size_t)(base + b) * NWORDS;
        r0 |= row[lane];
        if (lane < NWORDS - 64) r1 |= row[64 + lane];
    }
}

// One 128-box chunk. Caller has already executed vmwait22(), so D (this
// chunk's diag, issued ~1 chunk ago) and pv (rows kept 2 chunks ago) are
// complete; rows(c-1) and D(c+1) stay in flight.
__device__ __forceinline__ bool scan_body(int c, int lane, const u64* mat,
                                          Dx& D, u64 (&pv0)[8], u64 (&pv1)[8],
                                          unsigned& plive,
                                          u64& s0, u64& s1,
                                          u64& nxp0, u64& nxp1,
                                          u64& r0, u64& r1, int& cnt, int* kept,
                                          u64 lmask, int l1w) {
    const int base = c * 128;
    u64 k0 = 0, k1 = 0, nx0 = 0, nx1 = 0, nq0 = 0, nq1 = 0;

    // ---- greedy within the chunk (registers + readlane only) ----
    if ((s0 & s1) != ~0ull) {
        u64 rem0 = s0, rem1 = s1;
        while (cnt < POSTN) {
            int b;
            if (~rem0)      b = __ffsll((u64)~rem0) - 1;
            else if (~rem1) b = 64 + __ffsll((u64)~rem1) - 1;
            else break;
            if (lane == 0) kept[cnt] = base + b;
            ++cnt;
            if (b < 64) {
                rem0 |= rdl64(D.a[0], b) | (1ull << b);
                rem1 |= rdl64(D.a[1], b);
                nx0  |= rdl64(D.ax[0], b);
                nx1  |= rdl64(D.ax[1], b);
                nq0  |= rdl64(D.aq[0], b);
                nq1  |= rdl64(D.aq[1], b);
                k0   |= 1ull << b;
            } else {
                int bb = b - 64;
                rem0 |= rdl64(D.b[0], bb);
                rem1 |= rdl64(D.b[1], bb) | (1ull << bb);
                nx0  |= rdl64(D.bx[0], bb);
                nx1  |= rdl64(D.bx[1], bb);
                nq0  |= rdl64(D.bq[0], bb);
                nq1  |= rdl64(D.bq[1], bb);
                k1   |= 1ull << bb;
            }
        }
        if (cnt >= POSTN) return true;
    }

    // ---- fold rows(c-2) into r (values complete; pure register OR) ----
    {
        u64 f0 = 0ull, f1 = 0ull;
        #pragma unroll
        for (int j = 0; j < 8; ++j) {
            u64 m = 0ull - (u64)((plive >> j) & 1u);
            f0 |= pv0[j] & m;
            f1 |= pv1[j] & m;
        }
        r0 |= f0;
        r1 |= f1 & lmask;
    }

    // ---- issue D(c+2) into this (now-free) buffer, then rows(c) ----
    issue_d(c + 2, lane, mat, D);
    issue_rows(base, lane, mat, k0, k1, pv0, pv1, plive, r0, r1, l1w);

    // ---- s for chunk c+1:
    //   r  covers kept <= c-2 (just folded),
    //   nxp (nq of chunk c-1) covers kept at c-1,
    //   nx covers kept at c.  No memory dependence.
    {
        int w = 2 * c + 2;
        u64 t0 = ~0ull, t1 = ~0ull;
        if (w < 64)          { t0 = rdl64(r0, w);      t1 = rdl64(r0, w + 1); }
        else if (w < NWORDS) { t0 = rdl64(r1, w - 64); t1 = rdl64(r1, w - 63); }
        s0 = t0 | nx0 | nxp0;
        s1 = t1 | nx1 | nxp1;
        nxp0 = nq0;
        nxp1 = nq1;
    }
    return false;
}

// single-wave greedy scan, 128-box chunks, asm-pipelined:
//  - extended diag (6 words) ~2 chunks ahead, kept rows folded 2 chunks late
//  - one manual s_waitcnt vmcnt(22) per chunk; nothing younger is drained
__global__ __launch_bounds__(64, 1) void nms_scan_kernel(const u64* __restrict__ mat,
                                                         const u64* __restrict__ vmask,
                                                         const float4* __restrict__ tb,
                                                         float* __restrict__ out) {
    int lane = threadIdx.x;
    u64 r0 = ~vmask[lane];
    u64 r1 = (lane < NWORDS - 64) ? ~vmask[64 + lane] : ~0ull;
    __shared__ int kept[POSTN];
    int cnt = 0;
    const u64 lmask = (lane < NWORDS - 64) ? ~0ull : 0ull;
    const int l1w = (lane < NWORDS - 64) ? (64 + lane) : (NWORDS - 1);

    u64 pav0[8], pav1[8], pbv0[8], pbv1[8];
    unsigned liveA = 0u, liveB = 0u;
    Dx DA, DB;

    // prologue — VMEM queue (oldest->newest): D(0), padA(16), D(1), padB(16)
    issue_d(0, lane, mat, DA);
    #pragma unroll
    for (int j = 0; j < 8; ++j) {
        pav0[j] = aload_b64(mat + lane);
        pav1[j] = aload_b64(mat + lane);
    }
    issue_d(1, lane, mat, DB);
    #pragma unroll
    for (int j = 0; j < 8; ++j) {
        pbv0[j] = aload_b64(mat + lane);
        pbv1[j] = aload_b64(mat + lane);
    }

    u64 s0 = rdl64(r0, 0);
    u64 s1 = rdl64(r0, 1);
    u64 nxp0 = 0ull, nxp1 = 0ull;

    bool done = false;
    for (int p = 0; p < (NCHUNK + 1) / 2 && !done; ++p) {
        int c0 = 2 * p, c1 = 2 * p + 1;
        vmwait22();   // drains D(c0) + rows(c0-2); keeps D(c0+1) + rows(c0-1)
        done = scan_body(c0, lane, mat, DA, pav0, pav1, liveA,
                         s0, s1, nxp0, nxp1, r0, r1, cnt, kept, lmask, l1w);
        if (done || c1 >= NCHUNK) break;
        vmwait22();
        done = scan_body(c1, lane, mat, DB, pbv0, pbv1, liveB,
                         s0, s1, nxp0, nxp1, r0, r1, cnt, kept, lmask, l1w);
    }
    asm volatile("s_waitcnt vmcnt(0)" ::: "memory");   // drain before epilogue

    for (int r = lane; r < POSTN; r += 64) {
        float4 b = make_float4(0.f, 0.f, 0.f, 0.f);
        if (r < cnt) b = tb[kept[r]];
        float* o = out + r * 5;
        o[0] = 0.f; o[1] = b.x; o[2] = b.y; o[3] = b.z; o[4] = b.w;
    }
}

// ---------------- host launcher ----------------
extern "C" void kernel_launch(void* const* d_in, const int* in_sizes, int n_in,
                              void* d_out, int out_size, void* d_ws, size_t ws_size,
                              hipStream_t stream) {
    const float* scores = (const float*)d_in[0];
    const float* deltas = (const float*)d_in[1];
    const float* iminfo = (const float*)d_in[2];
    float* out = (float*)d_out;

    char* ws = (char*)d_ws;
    unsigned int* keys    = (unsigned int*)(ws + 0);          // 221184*4  = 884736
    unsigned int* hist256 = (unsigned int*)(ws + 884736);     // 256*4     = 1024
    unsigned int* state   = (unsigned int*)(ws + 885760);     // 64
    u64*          cand    = (u64*)(ws + 885824);              // 8192*8    = 65536
    float4*       tb      = (float4*)(ws + 951360);           // 6016*16   = 96256
    u64*          vmask   = (u64*)(ws + 1047616);             // 768
    u64*          mat     = (u64*)(ws + 1048384);             // 6016*94*8 = 4524032

    const int NB = N_ANCH / 256;   // 864 exactly

    init_kernel<<<17, 256, 0, stream>>>((float4*)hist256, (float4*)vmask);
    decode_kernel<<<NB, 256, 0, stream>>>(scores, deltas, iminfo, keys, hist256);
    midselect_kernel<<<1, 1024, 0, stream>>>(keys, hist256, state);
    compact_kernel<<<NB, 256, 0, stream>>>(keys, state, cand);
    rank_scatter_kernel<<<CAND_CAP / 32, 256, 0, stream>>>(cand, deltas, iminfo, tb, vmask);
    nms_matrix_kernel<<<dim3(NWORDS, NWORDS), 64, 0, stream>>>(tb, mat);
    nms_scan_kernel<<<1, 64, 0, stream>>>(mat, vmask, tb, out);
}

// Round 6
// 268.595 us; speedup vs baseline: 1.2616x; 1.2616x over previous
//
#include <hip/hip_runtime.h>

// ---------------- problem constants ----------------
#define N_ANCH 221184      // H*W*A = 128*192*9
#define HW     24576       // H*W
#define Wd     192
#define AA     9
#define TOPN   6000
#define POSTN  300
#define CAND_CAP 8192
#define NWORDS 94          // ceil(6016/64) words of suppression bits
#define NCHUNK 47          // 6016 / 128

typedef unsigned long long u64;
typedef __attribute__((ext_vector_type(2))) unsigned long long u64x2;

// anchor widths/heights (== ws2/hs2 of the reference, exact small ints)
__device__ const float c_aw[9] = {184.f,368.f,736.f,128.f,256.f,512.f, 88.f,176.f,352.f};
__device__ const float c_ah[9] = { 96.f,192.f,384.f,128.f,256.f,512.f,176.f,352.f,704.f};

// shared box decode — used by decode_kernel AND rank_scatter so the FP
// sequence (and thus every bit of the box) is identical in both places.
__device__ __forceinline__ float4 decode_box(int a, int cell,
                                             const float* __restrict__ deltas,
                                             float info0, float info1, float info2,
                                             bool* valid) {
    int h = cell / Wd;
    int w = cell - h * Wd;
    const float* db = deltas + (size_t)(4 * a) * HW + cell;
    float dx = db[0];
    float dy = db[HW];
    float dw = db[2 * HW];
    float dh = db[3 * HW];
    dw = fminf(fmaxf(dw, -10.f), 10.f);
    dh = fminf(fmaxf(dh, -10.f), 10.f);

    float ww = c_aw[a], hh = c_ah[a];
    float cx = 16.f * (float)w + 8.f;   // exact
    float cy = 16.f * (float)h + 8.f;   // exact

    float pcx = __fadd_rn(__fmul_rn(dx, ww), cx);
    float pcy = __fadd_rn(__fmul_rn(dy, hh), cy);
    float pw  = __fmul_rn(expf(dw), ww);
    float ph  = __fmul_rn(expf(dh), hh);
    float hpw = __fmul_rn(0.5f, pw);
    float hph = __fmul_rn(0.5f, ph);
    float x1 = __fsub_rn(pcx, hpw);
    float x2 = __fadd_rn(pcx, hpw);
    float y1 = __fsub_rn(pcy, hph);
    float y2 = __fadd_rn(pcy, hph);

    float xmax = __fsub_rn(info1, 1.f);
    float ymax = __fsub_rn(info0, 1.f);
    x1 = fminf(fmaxf(x1, 0.f), xmax);
    x2 = fminf(fmaxf(x2, 0.f), xmax);
    y1 = fminf(fmaxf(y1, 0.f), ymax);
    y2 = fminf(fmaxf(y2, 0.f), ymax);

    float msz = __fmul_rn(16.f, info2);
    *valid = (__fadd_rn(__fsub_rn(x2, x1), 1.f) >= msz) &&
             (__fadd_rn(__fsub_rn(y2, y1), 1.f) >= msz);
    return make_float4(x1, y1, x2, y2);
}

// ---------------- init: zero hist256+state+cand (contiguous) + vmask ------
#define ZA_F4 4164    // (1024 + 64 + 65536) / 16
#define ZB_F4 48      // 768 / 16
__global__ __launch_bounds__(256) void init_kernel(float4* zA, float4* zB) {
    int t = blockIdx.x * 256 + threadIdx.x;
    float4 z = make_float4(0.f, 0.f, 0.f, 0.f);
    if (t < ZA_F4) zA[t] = z;
    else if (t < ZA_F4 + ZB_F4) zB[t - ZA_F4] = z;
}

__global__ __launch_bounds__(256) void decode_kernel(const float* __restrict__ scores,
                                                     const float* __restrict__ deltas,
                                                     const float* __restrict__ iminfo,
                                                     unsigned int* __restrict__ keys,
                                                     unsigned int* __restrict__ hist256) {
    __shared__ unsigned int lh[256];
    lh[threadIdx.x] = 0u;
    __syncthreads();
    int t = blockIdx.x * 256 + threadIdx.x;
    int a = t / HW;
    int cell = t - a * HW;
    float score = scores[(AA + a) * HW + cell];
    bool valid;
    (void)decode_box(a, cell, deltas, iminfo[0], iminfo[1], iminfo[2], &valid);
    unsigned int sb = __float_as_uint(score);
    unsigned int key = valid ? ((sb & 0x80000000u) ? ~sb : (sb | 0x80000000u))
                             : 0x007FFFFFu;
    keys[t] = key;
    atomicAdd(&lh[key >> 24], 1u);
    __syncthreads();
    if (lh[threadIdx.x]) atomicAdd(&hist256[threadIdx.x], lh[threadIdx.x]);
}

__global__ __launch_bounds__(1024) void midselect_kernel(const unsigned int* __restrict__ keys,
                                                         const unsigned int* __restrict__ hist256,
                                                         unsigned int* __restrict__ state) {
    __shared__ unsigned int sfx[256];
    __shared__ unsigned int h2w[16][256];
    __shared__ unsigned int sP, sRank;
    int t = threadIdx.x;
    int wv = t >> 6;
    for (int i = t; i < 16 * 256; i += 1024) ((unsigned int*)h2w)[i] = 0u;
    if (t < 256) sfx[t] = hist256[t];
    __syncthreads();
    for (int d = 1; d < 256; d <<= 1) {
        unsigned int v = 0u;
        if (t < 256 && t + d < 256) v = sfx[t + d];
        __syncthreads();
        if (t < 256) sfx[t] += v;
        __syncthreads();
    }
    if (t < 256) {
        unsigned int ge = sfx[t];
        unsigned int gt = (t < 255) ? sfx[t + 1] : 0u;
        if (ge >= TOPN && gt < TOPN) { sP = (unsigned int)t; sRank = TOPN - gt; }
    }
    __syncthreads();
    unsigned int P = sP, rank = sRank;
    const uint4* k4 = (const uint4*)keys;
    for (int i = t; i < N_ANCH / 4; i += 1024) {
        uint4 v = k4[i];
        if ((v.x >> 24) == P) atomicAdd(&h2w[wv][(v.x >> 16) & 0xFFu], 1u);
        if ((v.y >> 24) == P) atomicAdd(&h2w[wv][(v.y >> 16) & 0xFFu], 1u);
        if ((v.z >> 24) == P) atomicAdd(&h2w[wv][(v.z >> 16) & 0xFFu], 1u);
        if ((v.w >> 24) == P) atomicAdd(&h2w[wv][(v.w >> 16) & 0xFFu], 1u);
    }
    __syncthreads();
    if (t < 256) {
        unsigned int s = 0;
        #pragma unroll
        for (int wvi = 0; wvi < 16; ++wvi) s += h2w[wvi][t];
        sfx[t] = s;
    }
    __syncthreads();
    for (int d = 1; d < 256; d <<= 1) {
        unsigned int v = 0u;
        if (t < 256 && t + d < 256) v = sfx[t + d];
        __syncthreads();
        if (t < 256) sfx[t] += v;
        __syncthreads();
    }
    if (t < 256) {
        unsigned int ge = sfx[t];
        unsigned int gt = (t < 255) ? sfx[t + 1] : 0u;
        if (ge >= rank && gt < rank) {
            state[0] = (P << 24) | ((unsigned int)t << 16);
            state[2] = 0u;
        }
    }
}

__global__ __launch_bounds__(256) void compact_kernel(const unsigned int* __restrict__ keys,
                                                      unsigned int* __restrict__ state,
                                                      u64* __restrict__ cand) {
    int t = blockIdx.x * 256 + threadIdx.x;
    unsigned int k = keys[t];
    unsigned int T = state[0];
    if (k >= T) {
        unsigned int pos = atomicAdd(&state[2], 1u);
        if (pos < CAND_CAP) {
            int a = t / HW;
            int cell = t - a * HW;
            unsigned int aidx = (unsigned int)(cell * 9 + a);
            cand[pos] = ((u64)k << 32) | (u64)(~aidx);
        }
    }
}

__global__ __launch_bounds__(256) void rank_scatter_kernel(const u64* __restrict__ cand,
                                                           const float* __restrict__ deltas,
                                                           const float* __restrict__ iminfo,
                                                           float4* __restrict__ tb,
                                                           u64* __restrict__ vmask) {
    __shared__ u64 s[CAND_CAP];
    for (int j = threadIdx.x; j < CAND_CAP; j += 256) s[j] = cand[j];
    int part = threadIdx.x & 7;
    int i = blockIdx.x * 32 + (threadIdx.x >> 3);
    u64 k = cand[i];
    __syncthreads();
    const ulonglong2* sv = (const ulonglong2*)s;
    unsigned int cnt = 0;
    #pragma unroll 8
    for (int jj = part; jj < CAND_CAP / 2; jj += 8) {
        ulonglong2 v = sv[jj];
        cnt += (v.x > k) ? 1u : 0u;
        cnt += (v.y > k) ? 1u : 0u;
    }
    cnt += __shfl_xor(cnt, 1);
    cnt += __shfl_xor(cnt, 2);
    cnt += __shfl_xor(cnt, 4);
    if (part == 0 && k != 0ull && cnt < TOPN) {
        unsigned int aidx = ~((unsigned int)k);
        int a = (int)(aidx % 9u);
        int cell = (int)(aidx / 9u);
        bool valid;
        float4 box = decode_box(a, cell, deltas, iminfo[0], iminfo[1], iminfo[2], &valid);
        tb[cnt] = box;
        if ((unsigned int)(k >> 32) != 0x007FFFFFu)
            atomicOr(&vmask[cnt >> 6], 1ull << (cnt & 63));
    }
}

// suppression bit-matrix, upper-triangle word-blocks only.
__global__ __launch_bounds__(64) void nms_matrix_kernel(const float4* __restrict__ tb,
                                                        u64* __restrict__ mat) {
    if (blockIdx.x < blockIdx.y) return;
    __shared__ float4 cb[64];
    int t = threadIdx.x;
    int c0 = blockIdx.x * 64;
    int col = c0 + t;
    cb[t] = (col < TOPN) ? tb[col] : make_float4(0.f, 0.f, 0.f, 0.f);
    __syncthreads();
    int row = blockIdx.y * 64 + t;
    if (row >= TOPN) return;
    float4 rb = tb[row];
    float rA = (rb.z - rb.x) * (rb.w - rb.y);
    u64 mask = 0ull;
    for (int c = 0; c < 64; ++c) {
        if (c0 + c >= TOPN) break;
        float4 b = cb[c];
        float lx = fmaxf(rb.x, b.x), ly = fmaxf(rb.y, b.y);
        float rx = fminf(rb.z, b.z), ry = fminf(rb.w, b.w);
        float iw = fmaxf(rx - lx, 0.f), ih = fmaxf(ry - ly, 0.f);
        float inter = iw * ih;
        float bA = (b.z - b.x) * (b.w - b.y);
        float iou = inter / ((rA + bA) - inter);
        if (iou > 0.7f) mask |= (1ull << c);
    }
    mat[(size_t)row * NWORDS + blockIdx.x] = mask;
}

// 64-bit readlane with wave-uniform index.
__device__ __forceinline__ u64 rdl64(u64 v, int l) {
    unsigned int lo = (unsigned int)__builtin_amdgcn_readlane((int)(unsigned int)v, l);
    unsigned int hi = (unsigned int)__builtin_amdgcn_readlane((int)(unsigned int)(v >> 32), l);
    return ((u64)hi << 32) | (u64)lo;
}

__device__ __forceinline__ u64x2 aload_b128(const u64* p) {
    u64x2 d;
    asm volatile("global_load_dwordx4 %0, %1, off"
                 : "=v"(d) : "v"((u64)(uintptr_t)p));
    return d;
}
__device__ __forceinline__ void lgkm0() {
    asm volatile("s_waitcnt lgkmcnt(0)" ::: "memory");
}
// manual counted wait + scheduler fence: rule #18 — hipcc may hoist
// register-only consumers (readlane) past an inline-asm waitcnt; the
// sched_barrier(0) pins them below the wait.
__device__ __forceinline__ void vmwait6_fenced() {
    asm volatile("s_waitcnt vmcnt(6)" ::: "memory");
    __builtin_amdgcn_sched_barrier(0);
}

// Extended diagonal block for chunk c, per lane:
//  a  = words 2c,2c+1   of rows c*128+lane / +64+lane  (this chunk's cols)
//  ax = words 2c+2,2c+3 (next chunk's cols -> nx)
//  aq = words 2c+4,2c+5 (next-next chunk's cols -> nq), clamped at the end
struct Dx { u64x2 a, ax, aq, b, bx, bq; };

__device__ __forceinline__ void issue_d(int c, int lane, const u64* mat, Dx& D) {
    int cc = (c < NCHUNK) ? c : (NCHUNK - 1);
    const u64* rowA = mat + (size_t)(cc * 128 + lane) * NWORDS;
    const u64* rowB = rowA + (size_t)64 * NWORDS;
    int o0 = 2 * cc;
    int o1 = (o0 + 2 <= NWORDS - 2) ? o0 + 2 : NWORDS - 2;
    int o2 = (o0 + 4 <= NWORDS - 2) ? o0 + 4 : NWORDS - 2;
    D.a  = aload_b128(rowA + o0);
    D.ax = aload_b128(rowA + o1);
    D.aq = aload_b128(rowA + o2);
    D.b  = aload_b128(rowB + o0);
    D.bx = aload_b128(rowB + o1);
    D.bq = aload_b128(rowB + o2);
}

#define DONEV 0x100000u
#define NPROP 4

// greedy wave's per-chunk body. Caller waited vmcnt(6) so D is complete.
__device__ __forceinline__ bool gbody(int c, int lane, const Dx& D,
                                      u64& s0, u64& s1, u64& nxp0, u64& nxp1,
                                      int& cnt, int* keptl,
                                      volatile u64* vr, volatile u64* vkm,
                                      volatile unsigned* vprog,
                                      volatile unsigned* vc0) {
    const int base = c * 128;
    u64 k0 = 0, k1 = 0, nx0 = 0, nx1 = 0, nq0 = 0, nq1 = 0;

    if ((s0 & s1) != ~0ull) {
        u64 rem0 = s0, rem1 = s1;
        while (cnt < POSTN) {
            int b;
            if (~rem0)      b = __ffsll((u64)~rem0) - 1;
            else if (~rem1) b = 64 + __ffsll((u64)~rem1) - 1;
            else break;
            if (lane == 0) keptl[cnt] = base + b;
            ++cnt;
            if (b < 64) {
                rem0 |= rdl64(D.a[0], b) | (1ull << b);
                rem1 |= rdl64(D.a[1], b);
                nx0  |= rdl64(D.ax[0], b);  nx1 |= rdl64(D.ax[1], b);
                nq0  |= rdl64(D.aq[0], b);  nq1 |= rdl64(D.aq[1], b);
                k0   |= 1ull << b;
            } else {
                int bb = b - 64;
                rem0 |= rdl64(D.b[0], bb);
                rem1 |= rdl64(D.b[1], bb) | (1ull << bb);
                nx0  |= rdl64(D.bx[0], bb); nx1 |= rdl64(D.bx[1], bb);
                nq0  |= rdl64(D.bq[0], bb); nq1 |= rdl64(D.bq[1], bb);
                k1   |= 1ull << bb;
            }
        }
        if (cnt >= POSTN) return true;
    }

    // publish kept mask, then progress (fenced so props see consistent data)
    if (lane == 0) { vkm[2 * c] = k0; vkm[2 * c + 1] = k1; }
    lgkm0();
    if (lane == 0) *vc0 = (unsigned)(c + 1);

    if (c + 1 < NCHUNK) {
        // gate: prop waves must have folded all chunks <= c-2
        int g = c - 2;
        if (g >= 0) {
            unsigned n0 = (unsigned)(g / 4) + 1u;
            unsigned n1 = (g >= 1) ? (unsigned)((g - 1) / 4) + 1u : 0u;
            unsigned n2 = (g >= 2) ? (unsigned)((g - 2) / 4) + 1u : 0u;
            unsigned n3 = (g >= 3) ? (unsigned)((g - 3) / 4) + 1u : 0u;
            for (;;) {
                unsigned p0 = vprog[0], p1 = vprog[1];
                unsigned p2 = vprog[2], p3 = vprog[3];
                if (p0 >= n0 && p1 >= n1 && p2 >= n2 && p3 >= n3) break;
                __builtin_amdgcn_s_sleep(1);
            }
        }
        const int wd = 2 * c + 2;
        u64 t0 = vr[wd]     | vr[96 + wd]     | vr[192 + wd]     | vr[288 + wd];
        u64 t1 = vr[wd + 1] | vr[96 + wd + 1] | vr[192 + wd + 1] | vr[288 + wd + 1];
        // r(<=c-2 guaranteed, possibly more — monotone superset of real kept
        // rows <= c, all duplicates of nx/nxp info) | kept@c-1 | kept@c
        s0 = t0 | nx0 | nxp0;
        s1 = t1 | nx1 | nxp1;
        nxp0 = nq0;
        nxp1 = nq1;
    }
    return false;
}

// 5-wave producer/consumer greedy scan.
//  wave 0: greedy over 47 chunks; only global traffic = asm-prefetched diag
//          (vmcnt(6) keeps next chunk's 6 loads in flight). s(c+1) built from
//          LDS partial-r + extended-diag registers -> row-load latency is OFF
//          the critical path.
//  waves 1-4: fold kept rows (chunk j -> wave 1+(j%4)) into private r, publish
//          to LDS. Batched independent loads (round-0 pattern), 4-way parallel.
__global__ __launch_bounds__(320, 1) void nms_scan_kernel(const u64* __restrict__ mat,
                                                          const u64* __restrict__ vmask,
                                                          const float4* __restrict__ tb,
                                                          float* __restrict__ out) {
    __shared__ int kept[POSTN];
    __shared__ u64 rfull[NPROP][96];       // partial r per prop wave (+pad)
    __shared__ u64 keptm[NCHUNK][2];
    __shared__ unsigned prog[NPROP];
    __shared__ unsigned c0prog;
    __shared__ int cntf;

    const int tid = threadIdx.x;
    const int wid = tid >> 6;
    const int lane = tid & 63;

    volatile u64* vr = &rfull[0][0];
    volatile u64* vkm = &keptm[0][0];
    volatile unsigned* vprog = prog;
    volatile unsigned* vc0 = &c0prog;

    u64 pr0 = 0ull, pr1 = 0ull;
    Dx DA, DB;
    if (wid == 0) {
        issue_d(0, lane, mat, DA);   // in flight across the barrier
    } else {
        const int w = wid - 1;
        if (w == 0) {
            pr0 = ~vmask[lane];
            pr1 = (lane < NWORDS - 64) ? ~vmask[64 + lane] : 0ull;
        }
        vr[w * 96 + lane] = pr0;
        if (lane < 32) vr[w * 96 + 64 + lane] = (lane < NWORDS - 64) ? pr1 : 0ull;
    }
    if (tid < NPROP) vprog[tid] = 0u;
    if (tid == 0) { *vc0 = 0u; cntf = 0; }
    __syncthreads();

    if (wid == 0) {
        // ---------------- greedy wave ----------------
        int cnt = 0;
        u64 s0 = vr[0], s1 = vr[1];         // ~vmask words 0,1
        u64 nxp0 = 0ull, nxp1 = 0ull;
        bool done = false;
        for (int p = 0; p < (NCHUNK + 1) / 2 && !done; ++p) {
            int c0 = 2 * p;
            issue_d(c0 + 1, lane, mat, DB);
            vmwait6_fenced();
            done = gbody(c0, lane, DA, s0, s1, nxp0, nxp1, cnt, kept,
                         vr, vkm, vprog, vc0);
            if (done || c0 + 1 >= NCHUNK) break;
            issue_d(c0 + 2, lane, mat, DA);
            vmwait6_fenced();
            done = gbody(c0 + 1, lane, DB, s0, s1, nxp0, nxp1, cnt, kept,
                         vr, vkm, vprog, vc0);
        }
        asm volatile("s_waitcnt vmcnt(0)" ::: "memory");
        if (lane == 0) cntf = cnt;
        lgkm0();
        if (lane == 0) *vc0 = DONEV;        // release prop waves
    } else {
        // ---------------- propagation waves ----------------
        const int w = wid - 1;
        const u64 lmask = (lane < NWORDS - 64) ? ~0ull : 0ull;
        const int l1w = (lane < NWORDS - 64) ? (64 + lane) : (NWORDS - 1);
        u64 r0 = pr0, r1 = pr1;
        for (int j = w; j < NCHUNK; j += NPROP) {
            bool dead = false;
            for (;;) {
                unsigned v = *vc0;
                if (v >= DONEV) { dead = true; break; }
                if (v > (unsigned)j) break;
                __builtin_amdgcn_s_sleep(1);
            }
            if (dead) break;                 // greedy wave exited; stop
            u64 k0 = vkm[2 * j], k1 = vkm[2 * j + 1];
            const int base = j * 128;
            while (k0 | k1) {
                int idxs[8];
                #pragma unroll
                for (int q = 0; q < 8; ++q) {
                    int b = -1;
                    if (k0)      { b = __ffsll(k0) - 1;      k0 &= k0 - 1; }
                    else if (k1) { b = 64 + __ffsll(k1) - 1; k1 &= k1 - 1; }
                    idxs[q] = b;
                }
                u64 v0[8], v1[8];
                #pragma unroll
                for (int q = 0; q < 8; ++q) {
                    v0[q] = 0ull; v1[q] = 0ull;
                    if (idxs[q] >= 0) {
                        const u64* row = mat + (size_t)(base + idxs[q]) * NWORDS;
                        v0[q] = row[lane];
                        v1[q] = row[l1w];
                    }
                }
                #pragma unroll
                for (int q = 0; q < 8; ++q) { r0 |= v0[q]; r1 |= v1[q] & lmask; }
            }
            // publish partial r (monotone OR — torn reads are still supersets
            // of the acked state), fence, then progress counter
            vr[w * 96 + lane] = r0;
            if (lane < NWORDS - 64) vr[w * 96 + 64 + lane] = r1;
            lgkm0();
            if (lane == 0) vprog[w] = (unsigned)((j - w) / NPROP) + 1u;
        }
    }

    __syncthreads();
    const int cn = cntf;
    for (int r = tid; r < POSTN; r += 320) {
        float4 b = make_float4(0.f, 0.f, 0.f, 0.f);
        if (r < cn) b = tb[kept[r]];
        float* o = out + r * 5;
        o[0] = 0.f; o[1] = b.x; o[2] = b.y; o[3] = b.z; o[4] = b.w;
    }
}

// ---------------- host launcher ----------------
extern "C" void kernel_launch(void* const* d_in, const int* in_sizes, int n_in,
                              void* d_out, int out_size, void* d_ws, size_t ws_size,
                              hipStream_t stream) {
    const float* scores = (const float*)d_in[0];
    const float* deltas = (const float*)d_in[1];
    const float* iminfo = (const float*)d_in[2];
    float* out = (float*)d_out;

    char* ws = (char*)d_ws;
    unsigned int* keys    = (unsigned int*)(ws + 0);          // 221184*4  = 884736
    unsigned int* hist256 = (unsigned int*)(ws + 884736);     // 256*4     = 1024
    unsigned int* state   = (unsigned int*)(ws + 885760);     // 64
    u64*          cand    = (u64*)(ws + 885824);              // 8192*8    = 65536
    float4*       tb      = (float4*)(ws + 951360);           // 6016*16   = 96256
    u64*          vmask   = (u64*)(ws + 1047616);             // 768
    u64*          mat     = (u64*)(ws + 1048384);             // 6016*94*8 = 4524032

    const int NB = N_ANCH / 256;   // 864 exactly

    init_kernel<<<17, 256, 0, stream>>>((float4*)hist256, (float4*)vmask);
    decode_kernel<<<NB, 256, 0, stream>>>(scores, deltas, iminfo, keys, hist256);
    midselect_kernel<<<1, 1024, 0, stream>>>(keys, hist256, state);
    compact_kernel<<<NB, 256, 0, stream>>>(keys, state, cand);
    rank_scatter_kernel<<<CAND_CAP / 32, 256, 0, stream>>>(cand, deltas, iminfo, tb, vmask);
    nms_matrix_kernel<<<dim3(NWORDS, NWORDS), 64, 0, stream>>>(tb, mat);
    nms_scan_kernel<<<1, 320, 0, stream>>>(mat, vmask, tb, out);
}